// Round 5
// baseline (324.963 us; speedup 1.0000x reference)
//
#include <hip/hip_runtime.h>

// GConvGRU (ChebConv K=1) + ReLU + Linear, fully fused, H0 = 0:
//   Z  = sigmoid(x@Wxz + bxz + bhz)
//   Ht = tanh(x@Wxh + bxh + bhh)          (R-gate cancels: R*H0 = 0)
//   out = relu((1-Z)*Ht) @ Wlin + blin
// edge_index / edge_weight mathematically unused (K=1) -> never read.
//
// R6: lane-transposed, all-register design (post-mortem R5: three
// different weight paths all ~55-63us kernel at ~18% VALUBusy / 38%
// occupancy -> latency-bound on in-loop ds_read/s_load chains, not any
// pipe's throughput):
//  * lane = j (hidden idx): each lane holds its weight COLUMN in 32
//    VGPRs (log2e and H-side x2 pre-folded), loaded once per wave.
//    Steady-state loop has NO LDS reads, NO scalar loads -> no lgkmcnt
//    dependence chains at all.
//  * wave halves own node pairs: per iteration 4 nodes via 8 broadcast
//    dwordx4 loads (half-wave uniform address -> 1-2 lines each).
//  * pk-FMA over k-PAIRS: v4f subregisters are k-adjacent, so v2f
//    operands come straight from the loaded float4s - no pack movs.
//  * j-reduction via 4x DPP row_shr + row_bcast15 adds (pure VALU pipe,
//    no LDS) -> sums land in lanes 31/63; masked float2 store.
//  * exp -> exp2 with log2e folded into weights/biases at init (1 ulp
//    class change only); epilogue is 2 elems/lane/iter vs R5's 128.
// grid: 16384 waves x iters quads each (blocked for locality).

typedef float v2f __attribute__((ext_vector_type(2)));
typedef float v4f __attribute__((ext_vector_type(4)));

constexpr int F  = 16;  // F_IN
constexpr int HD = 32;  // HID

template<int C>
__device__ __forceinline__ float dppadd(float v) {
    // v += dpp_move<C>(v), invalid lanes contribute 0 (bound_ctrl=1).
    int m = __builtin_amdgcn_update_dpp(0, __float_as_int(v), C, 0xf, 0xf, true);
    return v + __int_as_float(m);
}

__device__ __forceinline__ float redux32(float v) {
    v = dppadd<0x111>(v);   // row_shr:1
    v = dppadd<0x112>(v);   // row_shr:2
    v = dppadd<0x114>(v);   // row_shr:4
    v = dppadd<0x118>(v);   // row_shr:8  -> lane15/31/47/63 hold row sums
    v = dppadd<0x142>(v);   // row_bcast15 -> lanes 31/63 hold 32-group sum
    return v;
}

__global__ __launch_bounds__(256, 2) void gru_fused(
    const float* __restrict__ x,
    const float* __restrict__ Wxz, const float* __restrict__ bxz,
    const float* __restrict__ bhz,
    const float* __restrict__ Wxh, const float* __restrict__ bxh,
    const float* __restrict__ bhh,
    const float* __restrict__ Wlin, const float* __restrict__ blin,
    float* __restrict__ out, int n, int iters)
{
    const int tid  = threadIdx.x;
    const int lane = tid & 63;
    const int j    = lane & 31;   // hidden index owned by this lane
    const int half = lane >> 5;   // node-pair half of the wave
    const int wid  = (blockIdx.x * 256 + tid) >> 6;

    constexpr float L2E = 1.4426950408889634f;

    // Per-lane weight column j, folded constants. Lanes 0-31 read
    // contiguous 128B per k; lanes 32-63 broadcast the same addresses.
    v2f wz[F / 2], wh[F / 2];
    #pragma unroll
    for (int kp = 0; kp < F / 2; ++kp) {
        wz[kp] = (v2f){ Wxz[(2 * kp) * HD + j] * L2E,
                        Wxz[(2 * kp + 1) * HD + j] * L2E };
        wh[kp] = (v2f){ Wxh[(2 * kp) * HD + j] * (2.f * L2E),
                        Wxh[(2 * kp + 1) * HD + j] * (2.f * L2E) };
    }
    const float bz = (bxz[j] + bhz[j]) * L2E;
    const float bh = (bxh[j] + bhh[j]) * (2.f * L2E);
    const float wl = Wlin[j];
    const float b0 = blin[0];

    for (int it = 0; it < iters; ++it) {
        const int q  = wid * iters + it;   // quad (4-node group) index
        const int qb = q * 4;
        if (qb >= n) break;                // n % 4 == 0; wave-uniform

        // This half-wave's two nodes: 128B contiguous, 8 broadcast loads.
        const v4f* xp = reinterpret_cast<const v4f*>(
            x + (size_t)(qb + 2 * half) * F);
        const v4f a0 = xp[0], a1 = xp[1], a2 = xp[2], a3 = xp[3]; // node A
        const v4f c0 = xp[4], c1 = xp[5], c2 = xp[6], c3 = xp[7]; // node B

        // Accumulate over k-pairs: acc = {sum_even_k, sum_odd_k}.
        v2f AZ = {bz, 0.f}, AH = {bh, 0.f};
        v2f BZ = {bz, 0.f}, BH = {bh, 0.f};

        const v2f xa[8] = {
            __builtin_shufflevector(a0, a0, 0, 1), __builtin_shufflevector(a0, a0, 2, 3),
            __builtin_shufflevector(a1, a1, 0, 1), __builtin_shufflevector(a1, a1, 2, 3),
            __builtin_shufflevector(a2, a2, 0, 1), __builtin_shufflevector(a2, a2, 2, 3),
            __builtin_shufflevector(a3, a3, 0, 1), __builtin_shufflevector(a3, a3, 2, 3)};
        const v2f xb[8] = {
            __builtin_shufflevector(c0, c0, 0, 1), __builtin_shufflevector(c0, c0, 2, 3),
            __builtin_shufflevector(c1, c1, 0, 1), __builtin_shufflevector(c1, c1, 2, 3),
            __builtin_shufflevector(c2, c2, 0, 1), __builtin_shufflevector(c2, c2, 2, 3),
            __builtin_shufflevector(c3, c3, 0, 1), __builtin_shufflevector(c3, c3, 2, 3)};

        #pragma unroll
        for (int kp = 0; kp < 8; ++kp) {
            AZ = __builtin_elementwise_fma(xa[kp], wz[kp], AZ);
            AH = __builtin_elementwise_fma(xa[kp], wh[kp], AH);
            BZ = __builtin_elementwise_fma(xb[kp], wz[kp], BZ);
            BH = __builtin_elementwise_fma(xb[kp], wh[kp], BH);
        }

        // relu((1-Z)*tanh) = max(v-1,0) / ((1+u)(1+v)),
        // u = 2^az, v = 2^ah (ah pre-scaled by 2*log2e; clamp -> finite).
        float cA, cB;
        {
            const float az = AZ[0] + AZ[1];
            const float ah = AH[0] + AH[1];
            const float u = __builtin_amdgcn_exp2f(az);
            const float v = __builtin_amdgcn_exp2f(fminf(ah, 125.f));
            const float r = __builtin_amdgcn_rcpf((1.f + u) * (1.f + v));
            cA = fmaxf(v - 1.f, 0.f) * r * wl;
        }
        {
            const float az = BZ[0] + BZ[1];
            const float ah = BH[0] + BH[1];
            const float u = __builtin_amdgcn_exp2f(az);
            const float v = __builtin_amdgcn_exp2f(fminf(ah, 125.f));
            const float r = __builtin_amdgcn_rcpf((1.f + u) * (1.f + v));
            cB = fmaxf(v - 1.f, 0.f) * r * wl;
        }

        // Sum over j (32 lanes) on the VALU pipe; results in lanes 31/63.
        const float sA = redux32(cA);
        const float sB = redux32(cB);

        if ((lane & 31) == 31) {
            float2 o = make_float2(sA + b0, sB + b0);
            *reinterpret_cast<float2*>(out + qb + 2 * half) = o;
        }
    }
}

extern "C" void kernel_launch(void* const* d_in, const int* in_sizes, int n_in,
                              void* d_out, int out_size, void* d_ws, size_t ws_size,
                              hipStream_t stream) {
    // setup_inputs order:
    // 0:x 1:edge_index 2:edge_weight 3:Wxz 4:bxz 5:Whz 6:bhz 7:Wxr 8:bxr
    // 9:Whr 10:bhr 11:Wxh 12:bxh 13:Whh 14:bhh 15:Wlin 16:blin
    const float* x    = (const float*)d_in[0];
    const float* Wxz  = (const float*)d_in[3];
    const float* bxz  = (const float*)d_in[4];
    const float* bhz  = (const float*)d_in[6];
    const float* Wxh  = (const float*)d_in[11];
    const float* bxh  = (const float*)d_in[12];
    const float* bhh  = (const float*)d_in[14];
    const float* Wlin = (const float*)d_in[15];
    const float* blin = (const float*)d_in[16];
    float* out = (float*)d_out;

    const int n = in_sizes[0] / F;       // 1,000,000 nodes
    const int blocks = 4096;             // 16384 waves
    const int waves  = blocks * 4;
    const int quads  = n / 4;            // 250,000
    const int iters  = (quads + waves - 1) / waves;   // 16
    gru_fused<<<blocks, 256, 0, stream>>>(
        x, Wxz, bxz, bhz, Wxh, bxh, bhh, Wlin, blin, out, n, iters);
}

// Round 7
// 267.284 us; speedup vs baseline: 1.2158x; 1.2158x over previous
//
#include <hip/hip_runtime.h>

// GConvGRU (ChebConv K=1) + ReLU + Linear, fully fused, H0 = 0:
//   Z  = sigmoid(x@Wxz + bxz + bhz)
//   Ht = tanh(x@Wxh + bxh + bhh)          (R-gate cancels: R*H0 = 0)
//   out = relu((1-Z)*Ht) @ Wlin + blin
// edge_index / edge_weight mathematically unused (K=1) -> never read.
//
// R8 == R7 resubmitted (round-6 bench was an infra failure: "container
// failed twice", no profile; kernel audited for barrier-divergence /
// OOB / graph-capture hazards - none found).
//
// R7: j-split teams over the R5 structure (post-mortem R6: per-iter
// broadcast-load serialization, 230cyc compute vs 600cyc stall, model
// matched 107us; R1/R4/R5 all plateau 51-57us at ~17% VALUBusy with
// 3 different weight paths -> suspect too few independent streams +
// long per-wave serial chains):
//  * threads t and t+128 process the SAME 4 nodes; team0 owns jp 0-7,
//    team1 owns jp 8-15. Grid doubles to 7812 waves; per-wave serial
//    work (and ds-read chain count) halves. Partials combined via a
//    2KB LDS buffer + one extra __syncthreads.
//  * x loads issued BEFORE weight staging: global latency hides under
//    the stage + barrier instead of serializing after it.
//  * exp->exp2 with log2e (and H-side 2.0) folded into staged weights/
//    biases (validated in R6, absmax unchanged).
//  * instruction efficiency per node unchanged vs R5 (~8.6 wave-inst
//    per node, the best of all designs tried).

typedef float v2f __attribute__((ext_vector_type(2)));
typedef float v4f __attribute__((ext_vector_type(4)));

constexpr int F   = 16;  // F_IN
constexpr int HD  = 32;  // HID
constexpr int NPT = 4;   // nodes per thread-pair

__global__ __launch_bounds__(256, 2) void gru_fused(
    const float* __restrict__ x,
    const float* __restrict__ Wxz, const float* __restrict__ bxz,
    const float* __restrict__ bhz,
    const float* __restrict__ Wxh, const float* __restrict__ bxh,
    const float* __restrict__ bhh,
    const float* __restrict__ Wlin, const float* __restrict__ blin,
    float* __restrict__ out, int n)
{
    __shared__ __align__(16) v2f   sW[F * HD]; // {Wxz*log2e, Wxh*2*log2e}
    __shared__ __align__(16) v2f   sB[HD];     // folded biases, same scales
    __shared__ __align__(16) float sL[HD];     // Wlin
    __shared__ __align__(16) float4 sRes[128]; // team1 partials

    const int tid    = threadIdx.x;
    const int team   = tid >> 7;        // 0: jp 0-7 + store, 1: jp 8-15
    const int pr     = tid & 127;       // pair index within block
    const int base   = (blockIdx.x * 128 + pr) * NPT;
    const bool active = base < n;

    constexpr float L2E = 1.4426950408889634f;

    // Kick off this thread's x loads first: 256B contiguous, 16 dwordx4.
    // Latency overlaps the weight staging + barrier below.
    float4 xr[16];
    if (active) {
        const float4* px = reinterpret_cast<const float4*>(x + (size_t)base * F);
        #pragma unroll
        for (int q = 0; q < 16; ++q) xr[q] = px[q];
    }

    // Cooperative weight stage with folded constants.
    #pragma unroll
    for (int i = 0; i < 2; ++i) {
        const int idx = tid + i * 256;          // == k*HD + j, 0..511
        sW[idx] = (v2f){ Wxz[idx] * L2E, Wxh[idx] * (2.f * L2E) };
    }
    if (tid < HD) {
        sB[tid] = (v2f){ (bxz[tid] + bhz[tid]) * L2E,
                         (bxh[tid] + bhh[tid]) * (2.f * L2E) };
        sL[tid] = Wlin[tid];
    }
    __syncthreads();

    v2f res[2];
    res[0] = (v2f){0.f, 0.f};
    res[1] = (v2f){0.f, 0.f};

    if (active) {
        // Pack 4 nodes as node-pair v2f: xp[p][k] = {x[2p][k], x[2p+1][k]}.
        v2f xp[2][F];
        #pragma unroll
        for (int p = 0; p < 2; ++p) {
            #pragma unroll
            for (int q = 0; q < 4; ++q) {
                const float4 n0 = xr[8*p + q];
                const float4 n1 = xr[8*p + 4 + q];
                xp[p][4*q+0] = (v2f){n0.x, n1.x};
                xp[p][4*q+1] = (v2f){n0.y, n1.y};
                xp[p][4*q+2] = (v2f){n0.z, n1.z};
                xp[p][4*q+3] = (v2f){n0.w, n1.w};
            }
        }

        const int jp0 = team * 8;
        #pragma unroll
        for (int jj = 0; jj < 8; ++jj) {
            const int jp = jp0 + jj;
            const v4f bb = *reinterpret_cast<const v4f*>(&sB[2 * jp]);
            v2f aZ[2][2], aH[2][2];   // [j][node-pair]
            #pragma unroll
            for (int p = 0; p < 2; ++p) {
                aZ[0][p] = (v2f){bb[0], bb[0]};  aH[0][p] = (v2f){bb[1], bb[1]};
                aZ[1][p] = (v2f){bb[2], bb[2]};  aH[1][p] = (v2f){bb[3], bb[3]};
            }
            #pragma unroll
            for (int k = 0; k < F; ++k) {
                const v4f w = *reinterpret_cast<const v4f*>(&sW[k * HD + 2 * jp]);
                const v2f wz0 = {w[0], w[0]}, wh0 = {w[1], w[1]};
                const v2f wz1 = {w[2], w[2]}, wh1 = {w[3], w[3]};
                #pragma unroll
                for (int p = 0; p < 2; ++p) {
                    const v2f xk = xp[p][k];
                    aZ[0][p] = __builtin_elementwise_fma(xk, wz0, aZ[0][p]);
                    aH[0][p] = __builtin_elementwise_fma(xk, wh0, aH[0][p]);
                    aZ[1][p] = __builtin_elementwise_fma(xk, wz1, aZ[1][p]);
                    aH[1][p] = __builtin_elementwise_fma(xk, wh1, aH[1][p]);
                }
            }
            // relu((1-Z)*tanh) = max(v-1,0) / ((1+u)(1+v)),
            // u = 2^az, v = 2^ah (log2e & 2.0 pre-folded; clamp -> finite).
            const v2f wl = *reinterpret_cast<const v2f*>(&sL[2 * jp]);
            #pragma unroll
            for (int j2 = 0; j2 < 2; ++j2) {
                #pragma unroll
                for (int p = 0; p < 2; ++p) {
                    #pragma unroll
                    for (int h = 0; h < 2; ++h) {
                        const float az = aZ[j2][p][h];
                        const float ah = aH[j2][p][h];
                        const float u = __builtin_amdgcn_exp2f(az);
                        const float v = __builtin_amdgcn_exp2f(fminf(ah, 87.f));
                        const float r = __builtin_amdgcn_rcpf((1.f + u) * (1.f + v));
                        const float num = fmaxf(v - 1.f, 0.f);
                        res[p][h] = fmaf(num * r, wl[j2], res[p][h]);
                    }
                }
            }
        }
    }

    // Combine team partials: team1 -> LDS, team0 adds + stores.
    if (team == 1) {
        sRes[pr] = make_float4(res[0][0], res[0][1], res[1][0], res[1][1]);
    }
    __syncthreads();
    if (team == 0 && active) {
        const float4 o  = sRes[pr];
        const float  b0 = blin[0];
        float4 w;
        w.x = res[0][0] + o.x + b0;
        w.y = res[0][1] + o.y + b0;
        w.z = res[1][0] + o.z + b0;
        w.w = res[1][1] + o.w + b0;
        *reinterpret_cast<float4*>(out + base) = w;   // one dwordx4 store
    }
}

extern "C" void kernel_launch(void* const* d_in, const int* in_sizes, int n_in,
                              void* d_out, int out_size, void* d_ws, size_t ws_size,
                              hipStream_t stream) {
    // setup_inputs order:
    // 0:x 1:edge_index 2:edge_weight 3:Wxz 4:bxz 5:Whz 6:bhz 7:Wxr 8:bxr
    // 9:Whr 10:bhr 11:Wxh 12:bxh 13:Whh 14:bhh 15:Wlin 16:blin
    const float* x    = (const float*)d_in[0];
    const float* Wxz  = (const float*)d_in[3];
    const float* bxz  = (const float*)d_in[4];
    const float* bhz  = (const float*)d_in[6];
    const float* Wxh  = (const float*)d_in[11];
    const float* bxh  = (const float*)d_in[12];
    const float* bhh  = (const float*)d_in[14];
    const float* Wlin = (const float*)d_in[15];
    const float* blin = (const float*)d_in[16];
    float* out = (float*)d_out;

    const int n = in_sizes[0] / F;                 // 1,000,000 nodes
    const int pairs  = n / NPT;                    // 250,000
    const int blocks = (pairs + 127) / 128;        // 1954
    gru_fused<<<blocks, 256, 0, stream>>>(
        x, Wxz, bxz, bhz, Wxh, bxh, bhh, Wlin, blin, out, n);
}